// Round 2
// baseline (442.137 us; speedup 1.0000x reference)
//
#include <hip/hip_runtime.h>
#include <math.h>

// Problem constants: N=8, D=4, C=64, H=W=160
#define KTOT 1638400      // C*H*W
#define KV4  409600       // KTOT/4
#define PIX  25600        // H*W
#define NB_A 160          // gram blocks per n

// ---------------- Kernel A: Gram scores[n][d<=e] ----------------
// scores layout in ws: scores[n*10 + pairIdx], pairIdx maps (d<=e):
//   (0,0)=0 (0,1)=1 (0,2)=2 (0,3)=3 (1,1)=4 (1,2)=5 (1,3)=6 (2,2)=7 (2,3)=8 (3,3)=9
__device__ __forceinline__ float dot4(float4 a, float4 b) {
    return a.x*b.x + a.y*b.y + a.z*b.z + a.w*b.w;
}

__global__ __launch_bounds__(256) void gram_kernel(const float* __restrict__ x,
                                                   float* __restrict__ scores) {
    const int n   = blockIdx.y;
    const int tid = threadIdx.x;
    const float4* x4 = (const float4*)x;
    const float4* r0 = x4 + (size_t)(n*4+0)*KV4;
    const float4* r1 = x4 + (size_t)(n*4+1)*KV4;
    const float4* r2 = x4 + (size_t)(n*4+2)*KV4;
    const float4* r3 = x4 + (size_t)(n*4+3)*KV4;

    float s[10];
    #pragma unroll
    for (int i = 0; i < 10; i++) s[i] = 0.f;

    const int stride = NB_A * 256;
    for (int i = blockIdx.x*256 + tid; i < KV4; i += stride) {
        float4 a0 = r0[i], a1 = r1[i], a2 = r2[i], a3 = r3[i];
        s[0] += dot4(a0,a0);
        s[1] += dot4(a0,a1);
        s[2] += dot4(a0,a2);
        s[3] += dot4(a0,a3);
        s[4] += dot4(a1,a1);
        s[5] += dot4(a1,a2);
        s[6] += dot4(a1,a3);
        s[7] += dot4(a2,a2);
        s[8] += dot4(a2,a3);
        s[9] += dot4(a3,a3);
    }

    // wave-64 shuffle reduction
    #pragma unroll
    for (int i = 0; i < 10; i++) {
        float v = s[i];
        #pragma unroll
        for (int off = 32; off > 0; off >>= 1) v += __shfl_down(v, off, 64);
        s[i] = v;
    }

    __shared__ float red[4][10];
    const int wid = tid >> 6, lane = tid & 63;
    if (lane == 0) {
        #pragma unroll
        for (int i = 0; i < 10; i++) red[wid][i] = s[i];
    }
    __syncthreads();
    if (tid < 10) {
        float v = red[0][tid] + red[1][tid] + red[2][tid] + red[3][tid];
        atomicAdd(&scores[n*10 + tid], v);
    }
}

// ---------------- Kernel B: softmax over n + WeffT[n][q][c] ----------------
// WeffT[n][q][c] = sum_d conv_w[c*256 + d*64 + (q&63)] * (delta(d, q>>6) + l_corr[n,d,q>>6])
__global__ __launch_bounds__(64) void weff_kernel(const float* __restrict__ scores,
                                                  const float* __restrict__ w,
                                                  float* __restrict__ weffT) {
    const int q = blockIdx.x;   // 0..255
    const int n = blockIdx.y;   // 0..7
    const int t = threadIdx.x;  // 0..63

    __shared__ float T[16];     // T[d*4+e] = delta(d,e) + l_corr[n,d,e]
    if (t < 16) {
        const int d = t >> 2, e = t & 3;
        const int lo = min(d, e), hi = max(d, e);
        const int idx = lo*4 - lo*(lo-1)/2 + (hi - lo);
        float sv[8];
        float m = -3.0e38f;
        #pragma unroll
        for (int nn = 0; nn < 8; nn++) {
            sv[nn] = scores[nn*10 + idx];
            m = fmaxf(m, sv[nn]);
        }
        float sum = 0.f;
        #pragma unroll
        for (int nn = 0; nn < 8; nn++) sum += __expf(sv[nn] - m);
        const float l = __expf(sv[n] - m) / sum;
        T[t] = l + (d == e ? 1.f : 0.f);
    }
    __syncthreads();

    const int cp = q & 63, e = q >> 6;
    float v = 0.f;
    #pragma unroll
    for (int d = 0; d < 4; d++) v += w[t*256 + d*64 + cp] * T[d*4 + e];
    weffT[((size_t)(n*256 + q))*64 + t] = v;
}

// ---------------- Kernel C: out[n,c,p] = b[c] + sum_q WeffT[n][q][c] * x[n,q,p] ----
// 128 threads/block, 2 pixels per thread (float2) -> 256 pixels per block.
// Weight row address is block-uniform per q -> should scalarize to s_load +
// SGPR-operand v_fmac; each weight feeds 2 FMAs either way.
__global__ __launch_bounds__(128) void conv_kernel(const float* __restrict__ x,
                                                   const float* __restrict__ weffT,
                                                   const float* __restrict__ b,
                                                   float* __restrict__ out) {
    const int n = blockIdx.y;
    const int p = blockIdx.x*256 + threadIdx.x*2;

    float2 acc[64];
    #pragma unroll
    for (int c = 0; c < 64; c++) { float bv = b[c]; acc[c].x = bv; acc[c].y = bv; }

    const float* xp = x     + (size_t)n*256*PIX + p;
    const float* wp = weffT + (size_t)n*256*64;

    for (int q = 0; q < 256; q++) {
        const float2 v = *(const float2*)(xp + (size_t)q * PIX);
        const float* wr = wp + q*64;   // block-uniform address -> scalar loads
        #pragma unroll
        for (int c = 0; c < 64; c++) {
            acc[c].x += wr[c] * v.x;
            acc[c].y += wr[c] * v.y;
        }
    }

    float* op = out + (size_t)n*64*PIX + p;
    #pragma unroll
    for (int c = 0; c < 64; c++) *(float2*)(op + (size_t)c * PIX) = acc[c];
}

extern "C" void kernel_launch(void* const* d_in, const int* in_sizes, int n_in,
                              void* d_out, int out_size, void* d_ws, size_t ws_size,
                              hipStream_t stream) {
    const float* x = (const float*)d_in[0];   // (8,4,64,160,160)
    const float* w = (const float*)d_in[1];   // (64,256)
    const float* b = (const float*)d_in[2];   // (64,)
    float* out = (float*)d_out;               // (8,64,160,160)

    float* scores = (float*)d_ws;                       // 80 floats
    float* weffT  = (float*)((char*)d_ws + 1024);       // 8*256*64 floats = 512 KB

    // zero the score accumulators (ws is poisoned 0xAA before every launch)
    hipMemsetAsync(d_ws, 0, 1024, stream);

    gram_kernel<<<dim3(NB_A, 8), 256, 0, stream>>>(x, scores);
    weff_kernel<<<dim3(256, 8), 64, 0, stream>>>(scores, w, weffT);
    conv_kernel<<<dim3(PIX/256, 8), 128, 0, stream>>>(x, weffT, b, out);
}

// Round 3
// 385.456 us; speedup vs baseline: 1.1470x; 1.1470x over previous
//
#include <hip/hip_runtime.h>
#include <math.h>

// Problem constants: N=8, D=4, C=64, H=W=160
#define KTOT 1638400      // C*H*W
#define KV4  409600       // KTOT/4
#define PIX  25600        // H*W
#define NB_A 160          // gram blocks per n

// ---------------- Kernel A: Gram scores[n][d<=e] ----------------
// scores layout in ws: scores[n*10 + pairIdx], pairIdx maps (d<=e):
//   (0,0)=0 (0,1)=1 (0,2)=2 (0,3)=3 (1,1)=4 (1,2)=5 (1,3)=6 (2,2)=7 (2,3)=8 (3,3)=9
__device__ __forceinline__ float dot4(float4 a, float4 b) {
    return a.x*b.x + a.y*b.y + a.z*b.z + a.w*b.w;
}

__global__ __launch_bounds__(256) void gram_kernel(const float* __restrict__ x,
                                                   float* __restrict__ scores) {
    const int n   = blockIdx.y;
    const int tid = threadIdx.x;
    const float4* x4 = (const float4*)x;
    const float4* r0 = x4 + (size_t)(n*4+0)*KV4;
    const float4* r1 = x4 + (size_t)(n*4+1)*KV4;
    const float4* r2 = x4 + (size_t)(n*4+2)*KV4;
    const float4* r3 = x4 + (size_t)(n*4+3)*KV4;

    float s[10];
    #pragma unroll
    for (int i = 0; i < 10; i++) s[i] = 0.f;

    const int stride = NB_A * 256;
    for (int i = blockIdx.x*256 + tid; i < KV4; i += stride) {
        float4 a0 = r0[i], a1 = r1[i], a2 = r2[i], a3 = r3[i];
        s[0] += dot4(a0,a0);
        s[1] += dot4(a0,a1);
        s[2] += dot4(a0,a2);
        s[3] += dot4(a0,a3);
        s[4] += dot4(a1,a1);
        s[5] += dot4(a1,a2);
        s[6] += dot4(a1,a3);
        s[7] += dot4(a2,a2);
        s[8] += dot4(a2,a3);
        s[9] += dot4(a3,a3);
    }

    // wave-64 shuffle reduction
    #pragma unroll
    for (int i = 0; i < 10; i++) {
        float v = s[i];
        #pragma unroll
        for (int off = 32; off > 0; off >>= 1) v += __shfl_down(v, off, 64);
        s[i] = v;
    }

    __shared__ float red[4][10];
    const int wid = tid >> 6, lane = tid & 63;
    if (lane == 0) {
        #pragma unroll
        for (int i = 0; i < 10; i++) red[wid][i] = s[i];
    }
    __syncthreads();
    if (tid < 10) {
        float v = red[0][tid] + red[1][tid] + red[2][tid] + red[3][tid];
        atomicAdd(&scores[n*10 + tid], v);
    }
}

// ---------------- Kernel B: softmax over n + WeffT[n][z][q][32] ----------------
// Weff[n][c][q] = sum_d conv_w[c*256 + d*64 + (q&63)] * (delta(d, q>>6) + l_corr[n,d,q>>6])
// Stored transposed & c-split: weffT[((n*2+z)*256 + q)*32 + (c&31)], z = c>>5.
__global__ __launch_bounds__(64) void weff_kernel(const float* __restrict__ scores,
                                                  const float* __restrict__ w,
                                                  float* __restrict__ weffT) {
    const int q = blockIdx.x;   // 0..255
    const int n = blockIdx.y;   // 0..7
    const int t = threadIdx.x;  // 0..63 == c

    __shared__ float T[16];     // T[d*4+e] = delta(d,e) + l_corr[n,d,e]
    if (t < 16) {
        const int d = t >> 2, e = t & 3;
        const int lo = min(d, e), hi = max(d, e);
        const int idx = lo*4 - lo*(lo-1)/2 + (hi - lo);
        float sv[8];
        float m = -3.0e38f;
        #pragma unroll
        for (int nn = 0; nn < 8; nn++) {
            sv[nn] = scores[nn*10 + idx];
            m = fmaxf(m, sv[nn]);
        }
        float sum = 0.f;
        #pragma unroll
        for (int nn = 0; nn < 8; nn++) sum += __expf(sv[nn] - m);
        const float l = __expf(sv[n] - m) / sum;
        T[t] = l + (d == e ? 1.f : 0.f);
    }
    __syncthreads();

    const int cp = q & 63, e = q >> 6;
    float v = 0.f;
    #pragma unroll
    for (int d = 0; d < 4; d++) v += w[t*256 + d*64 + cp] * T[d*4 + e];
    weffT[(((size_t)n*2 + (t >> 5))*256 + q)*32 + (t & 31)] = v;
}

// ---------------- Kernel C: out[n,c,p] = b[c] + sum_q Weff[n][c][q] * x[n,q,p] ----
// 1 pixel/thread, 32 channels/thread (c-split via gridDim.z) -> 32 VGPR acc,
// 6400 waves (25/CU). Weight row address is block-uniform per q -> s_load +
// SGPR-operand v_fmac. x is L3-resident after gram, so the doubled x-read
// streams from Infinity Cache.
__global__ __launch_bounds__(256) void conv_kernel(const float* __restrict__ x,
                                                   const float* __restrict__ weffT,
                                                   const float* __restrict__ b,
                                                   float* __restrict__ out) {
    const int n = blockIdx.y;
    const int z = blockIdx.z;                 // c-half: 0 or 1
    const int p = blockIdx.x*256 + threadIdx.x;
    const int c0 = z*32;

    float acc[32];
    #pragma unroll
    for (int c = 0; c < 32; c++) acc[c] = b[c0 + c];

    const float* xp = x     + (size_t)n*256*PIX + p;
    const float* wp = weffT + ((size_t)(n*2 + z))*256*32;

    #pragma unroll 4
    for (int q = 0; q < 256; q++) {
        const float v = xp[(size_t)q * PIX];
        const float* wr = wp + q*32;   // block-uniform address -> scalar loads
        #pragma unroll
        for (int c = 0; c < 32; c++) acc[c] += wr[c] * v;
    }

    float* op = out + (size_t)n*64*PIX + (size_t)c0*PIX + p;
    #pragma unroll
    for (int c = 0; c < 32; c++) op[(size_t)c * PIX] = acc[c];
}

extern "C" void kernel_launch(void* const* d_in, const int* in_sizes, int n_in,
                              void* d_out, int out_size, void* d_ws, size_t ws_size,
                              hipStream_t stream) {
    const float* x = (const float*)d_in[0];   // (8,4,64,160,160)
    const float* w = (const float*)d_in[1];   // (64,256)
    const float* b = (const float*)d_in[2];   // (64,)
    float* out = (float*)d_out;               // (8,64,160,160)

    float* scores = (float*)d_ws;                       // 80 floats
    float* weffT  = (float*)((char*)d_ws + 1024);       // 8*2*256*32 floats = 512 KB

    // zero the score accumulators (ws is poisoned 0xAA before every launch)
    hipMemsetAsync(d_ws, 0, 1024, stream);

    gram_kernel<<<dim3(NB_A, 8), 256, 0, stream>>>(x, scores);
    weff_kernel<<<dim3(256, 8), 64, 0, stream>>>(scores, w, weffT);
    conv_kernel<<<dim3(PIX/256, 8, 2), 256, 0, stream>>>(x, weffT, b, out);
}